// Round 3
// baseline (267.877 us; speedup 1.0000x reference)
//
#include <hip/hip_runtime.h>
#include <cstdint>

// ---------- types ----------
typedef __attribute__((ext_vector_type(4))) float f32x4;
typedef __attribute__((ext_vector_type(8))) __bf16 bf16x8;
typedef __attribute__((ext_vector_type(8))) unsigned short u16x8;

// ---------- helpers ----------
__device__ __forceinline__ unsigned short f2bf(float f) {
    union { float f; unsigned u; } v; v.f = f;
    unsigned u = v.u + 0x7FFFu + ((v.u >> 16) & 1u);   // RNE
    return (unsigned short)(u >> 16);
}
__device__ __forceinline__ float bf2f(unsigned short h) {
    union { unsigned u; float f; } v; v.u = ((unsigned)h) << 16;
    return v.f;
}

__device__ __forceinline__ void gld_lds16(const void* g, void* l) {
    auto gp = reinterpret_cast<const __attribute__((address_space(1))) unsigned int*>(
        reinterpret_cast<uintptr_t>(g));
    auto lp = reinterpret_cast<__attribute__((address_space(3))) unsigned int*>(
        reinterpret_cast<uintptr_t>(l));
    __builtin_amdgcn_global_load_lds(gp, lp, 16, 0, 0);
}

// ---------- generic 128x128-tile GEMM core, C = A * B^T ----------
// A: MxK row-major (k-inner), B: NxK row-major (k-inner, i.e. B^T of the math B)
// BK=64 per tile, 4 waves in 2x2, each wave 64x64 via 4x4 frags of 16x16x32 bf16 MFMA.
// LDS staged via global_load_lds(16B) with XOR swizzle (source-preswizzled, read-swizzled).
template<int BF16OUT>
__device__ __forceinline__ void gemm_core(
    const unsigned short* A, int lda,
    const unsigned short* B, int ldb,
    void* C, int ldc,
    int ktiles, float scale,
    unsigned short* lA, unsigned short* lB)
{
    const int t = threadIdx.x;
    const int l = t & 63;
    const int w = t >> 6;
    const int wr = w >> 1, wc = w & 1;

    f32x4 acc[4][4];
#pragma unroll
    for (int i = 0; i < 4; ++i)
#pragma unroll
        for (int j = 0; j < 4; ++j)
#pragma unroll
            for (int e = 0; e < 4; ++e) acc[i][j][e] = 0.f;

    const int srow = t >> 3;      // 0..31
    const int schunk = t & 7;     // 16B chunk within 128B row

    for (int kt = 0; kt < ktiles; ++kt) {
        const int k0 = kt << 6;
        // stage A,B tiles (128 rows x 64 bf16), swizzled source -> linear LDS
#pragma unroll
        for (int p = 0; p < 4; ++p) {
            const int row = (p << 5) + srow;
            const int sc = schunk ^ (row & 7);
            gld_lds16(A + (size_t)row * lda + k0 + (sc << 3), lA + (p << 11) + (t << 3));
            gld_lds16(B + (size_t)row * ldb + k0 + (sc << 3), lB + (p << 11) + (t << 3));
        }
        __syncthreads();
#pragma unroll
        for (int kk = 0; kk < 2; ++kk) {
            bf16x8 af[4], bfr[4];
            const int c = (kk << 5) + ((l >> 4) << 3);
#pragma unroll
            for (int mf = 0; mf < 4; ++mf) {
                const int r = (wr << 6) + (mf << 4) + (l & 15);
                const int ad = ((r << 6) + c) ^ ((r & 7) << 3);
                af[mf] = *(const bf16x8*)(lA + ad);
            }
#pragma unroll
            for (int nf = 0; nf < 4; ++nf) {
                const int r = (wc << 6) + (nf << 4) + (l & 15);
                const int ad = ((r << 6) + c) ^ ((r & 7) << 3);
                bfr[nf] = *(const bf16x8*)(lB + ad);
            }
#pragma unroll
            for (int mf = 0; mf < 4; ++mf)
#pragma unroll
                for (int nf = 0; nf < 4; ++nf)
                    acc[mf][nf] = __builtin_amdgcn_mfma_f32_16x16x32_bf16(
                        af[mf], bfr[nf], acc[mf][nf], 0, 0, 0);
        }
        __syncthreads();
    }

    // epilogue: D[row][col], col = lane&15, row = (lane>>4)*4 + reg  (m89-verified)
#pragma unroll
    for (int mf = 0; mf < 4; ++mf)
#pragma unroll
        for (int nf = 0; nf < 4; ++nf)
#pragma unroll
            for (int j = 0; j < 4; ++j) {
                const int row = (wr << 6) + (mf << 4) + ((l >> 4) << 2) + j;
                const int col = (wc << 6) + (nf << 4) + (l & 15);
                const float v = acc[mf][nf][j] * scale;
                if (BF16OUT)
                    ((unsigned short*)C)[(size_t)row * ldc + col] = f2bf(v);
                else
                    ((float*)C)[(size_t)row * ldc + col] = v;
            }
}

// ---------- wrappers ----------
// x projection: out[m][n] = sum_k xb[m][k] * wt[n][k]   (wt = W^T, k-inner)
__global__ __launch_bounds__(256) void k_gemm_proj(
    const unsigned short* __restrict__ xb, const unsigned short* __restrict__ wt,
    unsigned short* __restrict__ out, float scale)
{
    __shared__ unsigned short lA[8192], lB[8192];
    gemm_core<1>(xb + (size_t)blockIdx.y * 128 * 1024, 1024,
                 wt + (size_t)blockIdx.x * 128 * 1024, 1024,
                 out + (size_t)blockIdx.y * 128 * 1024 + blockIdx.x * 128, 1024,
                 16, scale, lA, lB);
}

// Vt[d][t_global] = sum_k WvT[d][k] * xb[t][k]
__global__ __launch_bounds__(256) void k_gemm_vt(
    const unsigned short* __restrict__ wtv, const unsigned short* __restrict__ xb,
    unsigned short* __restrict__ vt)
{
    __shared__ unsigned short lA[8192], lB[8192];
    gemm_core<1>(wtv + (size_t)blockIdx.y * 128 * 1024, 1024,
                 xb + (size_t)blockIdx.x * 128 * 1024, 1024,
                 vt + (size_t)blockIdx.y * 128 * 8192 + blockIdx.x * 128, 8192,
                 16, 1.0f, lA, lB);
}

// causal scores: S[b][q][t'] = sum_d Qb[b,q][d] * Kb[b,t'][d]  (Q pre-scaled 1/32)
__global__ __launch_bounds__(256) void k_scores(
    const unsigned short* __restrict__ Qb, const unsigned short* __restrict__ Kb,
    unsigned short* __restrict__ S)
{
    const int kt = blockIdx.x, qt = blockIdx.y, b = blockIdx.z;
    if (kt > qt) return;
    __shared__ unsigned short lA[8192], lB[8192];
    gemm_core<1>(Qb + ((size_t)b * 2048 + qt * 128) * 1024, 1024,
                 Kb + ((size_t)b * 2048 + kt * 128) * 1024, 1024,
                 S + (size_t)b * 4194304 + (size_t)qt * 128 * 2048 + kt * 128, 2048,
                 16, 1.0f, lA, lB);
}

// PV: out[b,q][d] = sum_{t'<=q} P[b,q][t'] * Vt[d][b*2048+t'],  fp32 out
__global__ __launch_bounds__(256) void k_pv(
    const unsigned short* __restrict__ P, const unsigned short* __restrict__ Vt,
    float* __restrict__ out)
{
    const int dn = blockIdx.x, qt = blockIdx.y, b = blockIdx.z;
    __shared__ unsigned short lA[8192], lB[8192];
    gemm_core<0>(P + (size_t)b * 4194304 + (size_t)qt * 128 * 2048, 2048,
                 Vt + (size_t)dn * 128 * 8192 + b * 2048, 8192,
                 out + ((size_t)b * 2048 + qt * 128) * 1024 + dn * 128, 1024,
                 (qt + 1) * 2, 1.0f, lA, lB);
}

// ---------- cast / transpose ----------
__global__ __launch_bounds__(256) void k_cast_bf16(
    const float* __restrict__ in, unsigned short* __restrict__ out, int n8)
{
    const int i = blockIdx.x * 256 + threadIdx.x;
    if (i >= n8) return;
    const float4* p = (const float4*)in + (size_t)i * 2;
    const float4 a = p[0], b = p[1];
    u16x8 r;
    r[0] = f2bf(a.x); r[1] = f2bf(a.y); r[2] = f2bf(a.z); r[3] = f2bf(a.w);
    r[4] = f2bf(b.x); r[5] = f2bf(b.y); r[6] = f2bf(b.z); r[7] = f2bf(b.w);
    *(u16x8*)(out + (size_t)i * 8) = r;
}

// out[n][k] = in[k][n], 1024x1024, fp32 -> bf16
__global__ __launch_bounds__(256) void k_transpose_cast(
    const float* __restrict__ in, unsigned short* __restrict__ out)
{
    __shared__ float tile[32][33];
    const int bx = blockIdx.x * 32, by = blockIdx.y * 32;
    const int tx = threadIdx.x, ty = threadIdx.y;
    for (int r = ty; r < 32; r += 8)
        tile[r][tx] = in[(size_t)(by + r) * 1024 + bx + tx];
    __syncthreads();
    for (int r = ty; r < 32; r += 8)
        out[(size_t)(bx + r) * 1024 + by + tx] = f2bf(tile[tx][r]);
}

// ---------- causal row softmax over bf16 scores, in place, one wave per row ----------
__global__ __launch_bounds__(256) void k_softmax(unsigned short* __restrict__ S)
{
    const int w = threadIdx.x >> 6, l = threadIdx.x & 63;
    const int r = blockIdx.x * 4 + w;           // 0..8191
    const int b = r >> 11, lr = r & 2047;
    unsigned short* row = S + ((size_t)b << 22) + ((size_t)lr << 11);
    const int edge = ((lr >> 7) + 1) << 7;      // diag-tile right edge

    float v[32];
#pragma unroll
    for (int i = 0; i < 4; ++i) {
        const int c0 = (l << 3) + (i << 9);
        if (c0 < edge) {
            const u16x8 u = *(const u16x8*)(row + c0);
#pragma unroll
            for (int j = 0; j < 8; ++j)
                v[(i << 3) + j] = (c0 + j <= lr) ? bf2f(u[j]) : -3.0e38f;
        } else {
#pragma unroll
            for (int j = 0; j < 8; ++j) v[(i << 3) + j] = -3.0e38f;
        }
    }
    float m = v[0];
#pragma unroll
    for (int k = 1; k < 32; ++k) m = fmaxf(m, v[k]);
#pragma unroll
    for (int s = 32; s; s >>= 1) m = fmaxf(m, __shfl_xor(m, s, 64));
    float sum = 0.f;
#pragma unroll
    for (int k = 0; k < 32; ++k) { const float e = __expf(v[k] - m); v[k] = e; sum += e; }
#pragma unroll
    for (int s = 32; s; s >>= 1) sum += __shfl_xor(sum, s, 64);
    const float inv = 1.f / sum;
#pragma unroll
    for (int i = 0; i < 4; ++i) {
        const int c0 = (l << 3) + (i << 9);
        if (c0 < edge) {
            u16x8 o;
#pragma unroll
            for (int j = 0; j < 8; ++j) o[j] = f2bf(v[(i << 3) + j] * inv);
            *(u16x8*)(row + c0) = o;
        }
    }
}

// ---------- launch ----------
extern "C" void kernel_launch(void* const* d_in, const int* in_sizes, int n_in,
                              void* d_out, int out_size, void* d_ws, size_t ws_size,
                              hipStream_t stream)
{
    (void)in_sizes; (void)n_in; (void)out_size; (void)ws_size;
    const float* x  = (const float*)d_in[0];
    const float* Wq = (const float*)d_in[1];
    const float* Wk = (const float*)d_in[2];
    const float* Wv = (const float*)d_in[3];
    float* out = (float*)d_out;

    char* w = (char*)d_ws;
    unsigned short* xb  = (unsigned short*)(w);                    // 16 MiB
    unsigned short* wtq = (unsigned short*)(w + 16777216);         // 2 MiB
    unsigned short* wtk = (unsigned short*)(w + 18874368);         // 2 MiB
    unsigned short* wtv = (unsigned short*)(w + 20971520);         // 2 MiB
    unsigned short* Qb  = (unsigned short*)(w + 23068672);         // 16 MiB
    unsigned short* Kb  = (unsigned short*)(w + 39845888);         // 16 MiB
    unsigned short* Vt  = (unsigned short*)(w + 56623104);         // 16 MiB
    unsigned short* S   = (unsigned short*)(w + 73400320);         // 32 MiB (S then P, in place)

    k_cast_bf16<<<4096, 256, 0, stream>>>(x, xb, 1048576);
    const dim3 tb(32, 8);
    k_transpose_cast<<<dim3(32, 32), tb, 0, stream>>>(Wq, wtq);
    k_transpose_cast<<<dim3(32, 32), tb, 0, stream>>>(Wk, wtk);
    k_transpose_cast<<<dim3(32, 32), tb, 0, stream>>>(Wv, wtv);

    k_gemm_proj<<<dim3(8, 64), 256, 0, stream>>>(xb, wtq, Qb, 0.03125f); // Q * 1/sqrt(dk)
    k_gemm_proj<<<dim3(8, 64), 256, 0, stream>>>(xb, wtk, Kb, 1.0f);
    k_gemm_vt <<<dim3(64, 8), 256, 0, stream>>>(wtv, xb, Vt);

    k_scores  <<<dim3(16, 16, 4), 256, 0, stream>>>(Qb, Kb, S);
    k_softmax <<<2048, 256, 0, stream>>>(S);
    k_pv      <<<dim3(8, 16, 4), 256, 0, stream>>>(S, Vt, out);
}

// Round 5
// 228.794 us; speedup vs baseline: 1.1708x; 1.1708x over previous
//
#include <hip/hip_runtime.h>
#include <cstdint>

// ---------- types ----------
typedef __attribute__((ext_vector_type(4))) float f32x4;
typedef __attribute__((ext_vector_type(8))) __bf16 bf16x8;
typedef __attribute__((ext_vector_type(8))) unsigned short u16x8;

// ---------- helpers ----------
__device__ __forceinline__ unsigned short f2bf(float f) {
    union { float f; unsigned u; } v; v.f = f;
    unsigned u = v.u + 0x7FFFu + ((v.u >> 16) & 1u);   // RNE
    return (unsigned short)(u >> 16);
}
__device__ __forceinline__ float bf2f(unsigned short h) {
    union { unsigned u; float f; } v; v.u = ((unsigned)h) << 16;
    return v.f;
}

__device__ __forceinline__ void gld_lds16(const void* g, void* l) {
    auto gp = reinterpret_cast<const __attribute__((address_space(1))) unsigned int*>(
        reinterpret_cast<uintptr_t>(g));
    auto lp = reinterpret_cast<__attribute__((address_space(3))) unsigned int*>(
        reinterpret_cast<uintptr_t>(l));
    __builtin_amdgcn_global_load_lds(gp, lp, 16, 0, 0);
}

// ---------- 128x128-tile GEMM core, C = A * B^T ----------
// 8 waves (512 thr), wave grid 4(M) x 2(N), per-wave 32x64 via acc[2][4] of 16x16x32 bf16 MFMA.
// 2-phase loop (T3 minimum): STAGE(next) issued BEFORE compute(cur); ONE __syncthreads per K-tile
// (its vmcnt(0)+lgkmcnt(0) drain covers loads that had the whole MFMA phase to land).
// LDS double-buffered, XOR-swizzled (source-preswizzled chunk ^ row&7; HW-verified 0 conflicts).
template<int BF16OUT>
__device__ __forceinline__ void gemm8(
    const unsigned short* __restrict__ A, int lda,
    const unsigned short* __restrict__ B, int ldb,
    void* __restrict__ C, int ldc,
    int ktiles,
    unsigned short* lA, unsigned short* lB)   // each [2][128][64] shorts = 2x16KB
{
    const int t = threadIdx.x;
    const int l = t & 63;
    const int w = t >> 6;
    const int wr = w >> 1, wc = w & 1;   // 4x2 wave grid

    f32x4 acc[2][4];
#pragma unroll
    for (int i = 0; i < 2; ++i)
#pragma unroll
        for (int j = 0; j < 4; ++j)
#pragma unroll
            for (int e = 0; e < 4; ++e) acc[i][j][e] = 0.f;

    auto stage = [&](int p, int kt) {
        const int k0 = kt << 6;
#pragma unroll
        for (int i = 0; i < 2; ++i) {
            const int flat = t + (i << 9);          // 0..1023
            const int row = flat >> 3;              // 0..127
            const int sc = (flat & 7) ^ (row & 7);  // pre-swizzled source chunk
            gld_lds16(A + (size_t)row * lda + k0 + (sc << 3), lA + (p << 13) + (flat << 3));
            gld_lds16(B + (size_t)row * ldb + k0 + (sc << 3), lB + (p << 13) + (flat << 3));
        }
    };

    auto compute = [&](int p) {
#pragma unroll
        for (int kk = 0; kk < 2; ++kk) {
            bf16x8 af[2], bfr[4];
            const int c = (kk << 5) + ((l >> 4) << 3);
#pragma unroll
            for (int mf = 0; mf < 2; ++mf) {
                const int r = (wr << 5) + (mf << 4) + (l & 15);
                const int ad = (((r << 6) + c) ^ ((r & 7) << 3)) + (p << 13);
                af[mf] = *(const bf16x8*)(lA + ad);
            }
#pragma unroll
            for (int nf = 0; nf < 4; ++nf) {
                const int r = (wc << 6) + (nf << 4) + (l & 15);
                const int ad = (((r << 6) + c) ^ ((r & 7) << 3)) + (p << 13);
                bfr[nf] = *(const bf16x8*)(lB + ad);
            }
            __builtin_amdgcn_s_setprio(1);
#pragma unroll
            for (int mf = 0; mf < 2; ++mf)
#pragma unroll
                for (int nf = 0; nf < 4; ++nf)
                    acc[mf][nf] = __builtin_amdgcn_mfma_f32_16x16x32_bf16(
                        af[mf], bfr[nf], acc[mf][nf], 0, 0, 0);
            __builtin_amdgcn_s_setprio(0);
        }
    };

    stage(0, 0);
    __syncthreads();                       // vmcnt(0)+barrier: buf0 ready
    int p = 0;
    for (int kt = 0; kt < ktiles - 1; ++kt) {
        stage(p ^ 1, kt + 1);              // issue next-tile loads FIRST
        compute(p);                        // ds_read + MFMA hide the load latency
        __syncthreads();                   // drain + publish buf p^1; reads of p done
        p ^= 1;
    }
    compute(p);

    // epilogue: D[row][col], col=lane&15, row=(lane>>4)*4+reg (m89-verified)
#pragma unroll
    for (int mf = 0; mf < 2; ++mf)
#pragma unroll
        for (int nf = 0; nf < 4; ++nf)
#pragma unroll
            for (int j = 0; j < 4; ++j) {
                const int row = (wr << 5) + (mf << 4) + ((l >> 4) << 2) + j;
                const int col = (wc << 6) + (nf << 4) + (l & 15);
                const float v = acc[mf][nf][j];
                if (BF16OUT)
                    ((unsigned short*)C)[(size_t)row * ldc + col] = f2bf(v);
                else
                    ((float*)C)[(size_t)row * ldc + col] = v;
            }
}

// ---------- wrappers ----------
// merged Q|K projection: QK[m][n] = sum_k xb[m][k] * wtqk[n][k], n in [0,2048)
// (Wq^T rows pre-scaled by 1/sqrt(dk) at transpose time)
__global__ __launch_bounds__(512, 4) void k_gemm_qk(
    const unsigned short* __restrict__ xb, const unsigned short* __restrict__ wtqk,
    unsigned short* __restrict__ qk)
{
    __shared__ unsigned short lA[16384], lB[16384];
    gemm8<1>(xb + (size_t)blockIdx.y * 128 * 1024, 1024,
             wtqk + (size_t)blockIdx.x * 128 * 1024, 1024,
             qk + (size_t)blockIdx.y * 128 * 2048 + blockIdx.x * 128, 2048,
             16, lA, lB);
}

// Vt[d][t_global] = sum_k WvT[d][k] * xb[t][k]
__global__ __launch_bounds__(512, 4) void k_gemm_vt(
    const unsigned short* __restrict__ wtv, const unsigned short* __restrict__ xb,
    unsigned short* __restrict__ vt)
{
    __shared__ unsigned short lA[16384], lB[16384];
    gemm8<1>(wtv + (size_t)blockIdx.y * 128 * 1024, 1024,
             xb + (size_t)blockIdx.x * 128 * 1024, 1024,
             vt + (size_t)blockIdx.y * 128 * 8192 + blockIdx.x * 128, 8192,
             16, lA, lB);
}

// causal scores: S[b][q][t'] = sum_d Q[b,q][d] * K[b,t'][d]; Q = qk cols [0,1024), K = cols [1024,2048)
__global__ __launch_bounds__(512, 4) void k_scores(
    const unsigned short* __restrict__ qk, unsigned short* __restrict__ S)
{
    const int kt = blockIdx.x, qt = blockIdx.y, b = blockIdx.z;
    if (kt > qt) return;
    __shared__ unsigned short lA[16384], lB[16384];
    gemm8<1>(qk + ((size_t)b * 2048 + qt * 128) * 2048, 2048,
             qk + ((size_t)b * 2048 + kt * 128) * 2048 + 1024, 2048,
             S + (size_t)b * 4194304 + (size_t)qt * 128 * 2048 + kt * 128, 2048,
             16, lA, lB);
}

// PV: out[b,q][d] = sum_{t'<=q} P[b,q][t'] * Vt[d][b*2048+t']; paired qt tiles for load balance
__global__ __launch_bounds__(512, 4) void k_pv(
    const unsigned short* __restrict__ P, const unsigned short* __restrict__ Vt,
    float* __restrict__ out)
{
    const int dn = blockIdx.x, pr = blockIdx.y, b = blockIdx.z;
    __shared__ unsigned short lA[16384], lB[16384];
    const int q1 = pr, q2 = 15 - pr;       // (q1+1)+(q2+1) = 17 k-tiles of 128: constant work
    gemm8<0>(P + (size_t)b * 4194304 + (size_t)q1 * 128 * 2048, 2048,
             Vt + (size_t)dn * 128 * 8192 + b * 2048, 8192,
             out + ((size_t)b * 2048 + q1 * 128) * 1024 + dn * 128, 1024,
             (q1 + 1) * 2, lA, lB);
    __syncthreads();                        // all reads of LDS done before re-stage
    gemm8<0>(P + (size_t)b * 4194304 + (size_t)q2 * 128 * 2048, 2048,
             Vt + (size_t)dn * 128 * 8192 + b * 2048, 8192,
             out + ((size_t)b * 2048 + q2 * 128) * 1024 + dn * 128, 1024,
             (q2 + 1) * 2, lA, lB);
}

// ---------- cast / transpose ----------
__global__ __launch_bounds__(256) void k_cast_bf16(
    const float* __restrict__ in, unsigned short* __restrict__ out, int n8)
{
    const int i = blockIdx.x * 256 + threadIdx.x;
    if (i >= n8) return;
    const float4* p = (const float4*)in + (size_t)i * 2;
    const float4 a = p[0], b = p[1];
    u16x8 r;
    r[0] = f2bf(a.x); r[1] = f2bf(a.y); r[2] = f2bf(a.z); r[3] = f2bf(a.w);
    r[4] = f2bf(b.x); r[5] = f2bf(b.y); r[6] = f2bf(b.z); r[7] = f2bf(b.w);
    *(u16x8*)(out + (size_t)i * 8) = r;
}

// z=0: Wq^T * (1/32) -> wtqk rows [0,1024); z=1: Wk^T -> wtqk rows [1024,2048); z=2: Wv^T -> wtv
__global__ __launch_bounds__(256) void k_transpose3(
    const float* __restrict__ Wq, const float* __restrict__ Wk, const float* __restrict__ Wv,
    unsigned short* __restrict__ wtqk, unsigned short* __restrict__ wtv)
{
    __shared__ float tile[32][33];
    const int z = blockIdx.z;
    const float* in = (z == 0) ? Wq : (z == 1) ? Wk : Wv;
    unsigned short* out = (z < 2) ? (wtqk + (size_t)z * 1048576) : wtv;
    const float s = (z == 0) ? 0.03125f : 1.0f;
    const int bx = blockIdx.x * 32, by = blockIdx.y * 32;
    const int tx = threadIdx.x, ty = threadIdx.y;
    for (int r = ty; r < 32; r += 8)
        tile[r][tx] = in[(size_t)(by + r) * 1024 + bx + tx];
    __syncthreads();
    for (int r = ty; r < 32; r += 8)
        out[(size_t)(bx + r) * 1024 + by + tx] = f2bf(tile[tx][r] * s);
}

// ---------- causal row softmax over bf16 scores, in place, one wave per row ----------
__global__ __launch_bounds__(256) void k_softmax(unsigned short* __restrict__ S)
{
    const int w = threadIdx.x >> 6, l = threadIdx.x & 63;
    const int r = blockIdx.x * 4 + w;           // 0..8191
    const int b = r >> 11, lr = r & 2047;
    unsigned short* row = S + ((size_t)b << 22) + ((size_t)lr << 11);
    const int edge = ((lr >> 7) + 1) << 7;      // diag-tile right edge

    float v[32];
#pragma unroll
    for (int i = 0; i < 4; ++i) {
        const int c0 = (l << 3) + (i << 9);
        if (c0 < edge) {
            const u16x8 u = *(const u16x8*)(row + c0);
#pragma unroll
            for (int j = 0; j < 8; ++j)
                v[(i << 3) + j] = (c0 + j <= lr) ? bf2f(u[j]) : -3.0e38f;
        } else {
#pragma unroll
            for (int j = 0; j < 8; ++j) v[(i << 3) + j] = -3.0e38f;
        }
    }
    float m = v[0];
#pragma unroll
    for (int k = 1; k < 32; ++k) m = fmaxf(m, v[k]);
#pragma unroll
    for (int s = 32; s; s >>= 1) m = fmaxf(m, __shfl_xor(m, s, 64));
    float sum = 0.f;
#pragma unroll
    for (int k = 0; k < 32; ++k) { const float e = __expf(v[k] - m); v[k] = e; sum += e; }
#pragma unroll
    for (int s = 32; s; s >>= 1) sum += __shfl_xor(sum, s, 64);
    const float inv = 1.f / sum;
#pragma unroll
    for (int i = 0; i < 4; ++i) {
        const int c0 = (l << 3) + (i << 9);
        if (c0 < edge) {
            u16x8 o;
#pragma unroll
            for (int j = 0; j < 8; ++j) o[j] = f2bf(v[(i << 3) + j] * inv);
            *(u16x8*)(row + c0) = o;
        }
    }
}

// ---------- launch ----------
extern "C" void kernel_launch(void* const* d_in, const int* in_sizes, int n_in,
                              void* d_out, int out_size, void* d_ws, size_t ws_size,
                              hipStream_t stream)
{
    (void)in_sizes; (void)n_in; (void)out_size; (void)ws_size;
    const float* x  = (const float*)d_in[0];
    const float* Wq = (const float*)d_in[1];
    const float* Wk = (const float*)d_in[2];
    const float* Wv = (const float*)d_in[3];
    float* out = (float*)d_out;

    char* w = (char*)d_ws;
    unsigned short* xb   = (unsigned short*)(w);                  // 16 MiB
    unsigned short* wtqk = (unsigned short*)(w + 16777216);       //  4 MiB (Wq^T/32 | Wk^T)
    unsigned short* wtv  = (unsigned short*)(w + 20971520);       //  2 MiB
    unsigned short* QK   = (unsigned short*)(w + 23068672);       // 32 MiB (Q | K per row)
    unsigned short* Vt   = (unsigned short*)(w + 56623104);       // 16 MiB
    unsigned short* S    = (unsigned short*)(w + 73400320);       // 32 MiB (S then P in place)

    k_cast_bf16<<<4096, 256, 0, stream>>>(x, xb, 1048576);
    k_transpose3<<<dim3(32, 32, 3), dim3(32, 8), 0, stream>>>(Wq, Wk, Wv, wtqk, wtv);

    k_gemm_qk<<<dim3(16, 64), 512, 0, stream>>>(xb, wtqk, QK);   // 1024 blocks
    k_gemm_vt<<<dim3(64, 8), 512, 0, stream>>>(wtv, xb, Vt);     //  512 blocks

    k_scores <<<dim3(16, 16, 4), 512, 0, stream>>>(QK, S);       //  544 active blocks
    k_softmax<<<2048, 256, 0, stream>>>(S);
    k_pv     <<<dim3(8, 8, 4), 512, 0, stream>>>(S, Vt, out);    //  256 balanced blocks
}